// Round 1
// 556.507 us; speedup vs baseline: 1.1061x; 1.1061x over previous
//
#include <hip/hip_runtime.h>
#include <hip/hip_bf16.h>

// Problem constants (fixed shapes from setup_inputs)
#define M_DIM 8192   // B*S = 4*2048
#define N_DIM 4096   // D_OUT
#define DK    4096   // D_IN
#define R_DIM 64
#define KX    4160   // DK + R_DIM (K-extended GEMM)
#define SPLITK 8
#define KCHUNK (DK / SPLITK)  // 512
// SCALE = ALPHA/K = 16/16 = 1.0

// main gemm tiling: 256x256 tile, BK=32, 3-deep LDS ring, 8 waves (2Mx4N)
#define BM 256
#define BN 256
#define BK 32
#define NT (KX / BK)            // 130 K-tiles
#define ATILE (BM * BK)         // 8192 shorts = 16 KB per operand per buffer
#define BUFS (2 * ATILE)        // 16384 shorts per ring slot (A + B)

typedef __bf16 bf16x8 __attribute__((ext_vector_type(8)));
typedef float f32x4 __attribute__((ext_vector_type(4)));
typedef unsigned short ushort8 __attribute__((ext_vector_type(8)));

__device__ __forceinline__ unsigned short f2bf_rne(float f) {
  union { float f; unsigned int u; } v; v.f = f;
  unsigned int u = v.u;
  return (unsigned short)((u + 0x7fffu + ((u >> 16) & 1u)) >> 16);
}

// async global->LDS, 16B per lane; lds dest is wave-uniform base + lane*16
__device__ __forceinline__ void load16_to_lds(const void* g, void* l) {
  __builtin_amdgcn_global_load_lds(
      (__attribute__((address_space(1))) void*)(unsigned long long)(const char*)g,
      (__attribute__((address_space(3))) void*)(unsigned int)(unsigned long long)(char*)l,
      16, 0, 0);
}

// ---------------- fp32 -> bf16 conversion into strided layout ----------------
__global__ __launch_bounds__(256) void cvt_bf16_kernel(
    const float* __restrict__ src, unsigned short* __restrict__ dst,
    int shift, int mask, int rowstride, int coloff, long long total) {
  long long idx = ((long long)blockIdx.x * 256 + threadIdx.x) * 8;
  if (idx >= total) return;
  long long row = idx >> shift;
  int col = (int)(idx & mask);
  float4 f0 = *(const float4*)(src + idx);
  float4 f1 = *(const float4*)(src + idx + 4);
  ushort8 o;
  o[0] = f2bf_rne(f0.x); o[1] = f2bf_rne(f0.y);
  o[2] = f2bf_rne(f0.z); o[3] = f2bf_rne(f0.w);
  o[4] = f2bf_rne(f1.x); o[5] = f2bf_rne(f1.y);
  o[6] = f2bf_rne(f1.z); o[7] = f2bf_rne(f1.w);
  *(ushort8*)(dst + row * (long long)rowstride + coloff + col) = o;
}

// ---------------- z partials: zpart[kc] = xext[:, kc*512:(kc+1)*512] @ Abf^T ----------------
__global__ __launch_bounds__(256) void zgemm_kernel(
    const unsigned short* __restrict__ Xg,   // [M_DIM][KX] bf16
    const unsigned short* __restrict__ Ab,   // [R_DIM][DK] bf16
    float* __restrict__ zpart) {             // [SPLITK][M_DIM][64] fp32
  __shared__ unsigned short As[128][32];  // 8 KB (x rows)
  __shared__ unsigned short Bs[64][32];   // 4 KB (A rows)

  const int tid = threadIdx.x;
  const int wave = tid >> 6;
  const int lane = tid & 63;
  const int rowBase = blockIdx.x * 128;
  const int kc = blockIdx.y;
  const int kBase = kc * KCHUNK;
  const int wm = wave * 32;

  const int c0 = wave, c1 = wave + 4;
  const int srow = lane >> 2;
  const int sseg = (lane & 3) * 8;

  const unsigned short* aP0 = Xg + (size_t)(rowBase + c0 * 16 + srow) * KX + kBase + sseg;
  const unsigned short* aP1 = Xg + (size_t)(rowBase + c1 * 16 + srow) * KX + kBase + sseg;
  const unsigned short* bP0 = Ab + (size_t)(wave * 16 + srow) * DK + kBase + sseg;
  unsigned short* aL0 = &As[c0 * 16][0];
  unsigned short* aL1 = &As[c1 * 16][0];
  unsigned short* bL0 = &Bs[wave * 16][0];

  f32x4 acc[2][4] = {};
  const int fr = lane & 15;
  const int fk = (lane >> 4) * 8;

  for (int k0 = 0; k0 < KCHUNK; k0 += 32) {
    __syncthreads();
    load16_to_lds(aP0 + k0, aL0);
    load16_to_lds(aP1 + k0, aL1);
    load16_to_lds(bP0 + k0, bL0);
    __syncthreads();

    bf16x8 afrag[2], bfrag[4];
#pragma unroll
    for (int i = 0; i < 2; ++i)
      afrag[i] = *(const bf16x8*)&As[wm + i * 16 + fr][fk];
#pragma unroll
    for (int j = 0; j < 4; ++j)
      bfrag[j] = *(const bf16x8*)&Bs[j * 16 + fr][fk];
#pragma unroll
    for (int i = 0; i < 2; ++i)
#pragma unroll
      for (int j = 0; j < 4; ++j)
        acc[i][j] = __builtin_amdgcn_mfma_f32_16x16x32_bf16(afrag[i], bfrag[j],
                                                            acc[i][j], 0, 0, 0);
  }

  const int quad = lane >> 4;
#pragma unroll
  for (int j = 0; j < 4; ++j) {
    int col = j * 16 + fr;
#pragma unroll
    for (int i = 0; i < 2; ++i) {
      int row0 = rowBase + wm + i * 16 + quad * 4;
#pragma unroll
      for (int r = 0; r < 4; ++r)
        zpart[((size_t)kc * M_DIM + row0 + r) * R_DIM + col] = acc[i][j][r];
    }
  }
}

// ---------------- reduce partials, soft top-k mask, write bf16 into x_ext tail ----------------
__global__ __launch_bounds__(256) void mask_kernel(
    const float* __restrict__ zpart, unsigned short* __restrict__ xext) {
  const int wave = threadIdx.x >> 6;
  const int lane = threadIdx.x & 63;
  const int row = blockIdx.x * 4 + wave;

  float v = 0.f;
#pragma unroll
  for (int k = 0; k < SPLITK; ++k)
    v += zpart[((size_t)k * M_DIM + row) * R_DIM + lane];

  float a = fabsf(v);
  // rank-select the 16th-largest |z| (tie-safe): cnt_gt <= 15 < cnt_ge
  int cnt_gt = 0, cnt_ge = 0;
#pragma unroll
  for (int i = 0; i < 64; ++i) {
    float o = __shfl(a, i);
    cnt_gt += (o > a) ? 1 : 0;
    cnt_ge += (o >= a) ? 1 : 0;
  }
  float cand = (cnt_gt <= 15 && cnt_ge > 15) ? a : -1.f;
#pragma unroll
  for (int off = 32; off; off >>= 1) cand = fmaxf(cand, __shfl_xor(cand, off));
  float thr = cand;
  float mask = 1.f / (1.f + __expf(-(a - thr) * 10.0f));  // TEMP=0.1
  xext[(size_t)row * KX + DK + lane] = f2bf_rne(v * mask);  // SCALE == 1.0
}

// ---------------- main GEMM: out[m][n] = sum_k xext[m][k]*wext[n][k] + bias[n] ----------------
// 256x256 tile, BK=32, 8 waves (2Mx4N), 3-deep LDS ring with counted vmcnt
// (T3/T4 minimum schedule), slot-XOR LDS swizzle (T2, both-sides per rule 21),
// setprio around MFMA cluster (T5), bijective XCD blockIdx swizzle (T1).
__global__ __launch_bounds__(512, 2) void gemm_kernel(
    const unsigned short* __restrict__ Ag,   // [M_DIM][KX] bf16
    const unsigned short* __restrict__ Bg,   // [N_DIM][KX] bf16
    const float* __restrict__ bias,
    float* __restrict__ out) {
  extern __shared__ unsigned short sm[];  // 3 * BUFS shorts = 96 KB

  const int tid = threadIdx.x;
  const int w = tid >> 6;
  const int lane = tid & 63;

  // T1: 512 blocks = 8 XCDs x 64; each XCD gets 4 consecutive bm rows
  const int bid = blockIdx.x;
  const int swz = (bid & 7) * 64 + (bid >> 3);
  const int bm = swz >> 4;   // 0..31
  const int bn = swz & 15;   // 0..15
  const int rowBase = bm * BM;
  const int colBase = bn * BN;

  // wave tile: 2 (M) x 4 (N); per-wave output 128x64
  const int wm = (w >> 2) * 128;
  const int wn = (w & 3) * 64;

  // ---- staging setup -------------------------------------------------------
  // LDS dest is linear (wave-uniform base + lane*16B) -> lane L writes
  // row (chunk*16 + L>>2), 16B-slot (L&3). To realize the read-side swizzle
  // slot' = slot ^ ((row>>1)&3), pre-swizzle the GLOBAL source segment.
  const int srow = lane >> 2;                                // 0..15
  const int sseg = (((lane & 3) ^ ((lane >> 3) & 3)) * 8);   // swizzled 8-short seg
  const int c0 = w * 2, c1 = w * 2 + 1;                      // 16-row chunks
  const unsigned short* aS0 = Ag + (size_t)(rowBase + c0 * 16 + srow) * KX + sseg;
  const unsigned short* aS1 = Ag + (size_t)(rowBase + c1 * 16 + srow) * KX + sseg;
  const unsigned short* bS0 = Bg + (size_t)(colBase + c0 * 16 + srow) * KX + sseg;
  const unsigned short* bS1 = Bg + (size_t)(colBase + c1 * 16 + srow) * KX + sseg;
  const int aD0 = c0 * 512, aD1 = c1 * 512;                  // shorts, wave-uniform
  const int bD0 = ATILE + c0 * 512, bD1 = ATILE + c1 * 512;

#define STAGE(bufS, koff)                                \
  do {                                                   \
    load16_to_lds(aS0 + (koff), &sm[(bufS) + aD0]);      \
    load16_to_lds(aS1 + (koff), &sm[(bufS) + aD1]);      \
    load16_to_lds(bS0 + (koff), &sm[(bufS) + bD0]);      \
    load16_to_lds(bS1 + (koff), &sm[(bufS) + bD1]);      \
  } while (0)

  // ---- prologue: fill the 3-deep ring (tiles 0,1,2), 12 loads in flight ----
  STAGE(0 * BUFS, 0);
  STAGE(1 * BUFS, 32);
  STAGE(2 * BUFS, 64);
  asm volatile("s_waitcnt vmcnt(8)" ::: "memory");   // tile 0 landed; 1,2 in flight
  __builtin_amdgcn_sched_barrier(0);
  __builtin_amdgcn_s_barrier();
  __builtin_amdgcn_sched_barrier(0);

  // ---- main loop -----------------------------------------------------------
  f32x4 acc[8][4] = {};
  const int fr = lane & 15;
  const int q = lane >> 4;
  const int rdc = ((q ^ ((fr >> 1) & 3)) * 8);  // T2 read-side XOR (2-way = free)

  int cur = 0;      // ring slot holding tile t
  int koff = 96;    // k-offset (shorts) of next tile to stage (tile 3)
  for (int t = 0; t < NT; ++t) {
    const int bufS = cur * BUFS;

    // ds_read all fragments for this tile (12 x ds_read_b128 per lane)
    bf16x8 af[8], bf[4];
#pragma unroll
    for (int i = 0; i < 8; ++i)
      af[i] = *(const bf16x8*)&sm[bufS + (wm + i * 16 + fr) * 32 + rdc];
#pragma unroll
    for (int j = 0; j < 4; ++j)
      bf[j] = *(const bf16x8*)&sm[bufS + ATILE + (wn + j * 16 + fr) * 32 + rdc];

    // my reads complete, then ALL waves' reads complete -> slot is free
    asm volatile("s_waitcnt lgkmcnt(0)" ::: "memory");
    __builtin_amdgcn_sched_barrier(0);
    __builtin_amdgcn_s_barrier();
    __builtin_amdgcn_sched_barrier(0);

    // refill the just-freed slot with tile t+3 (loads fly during MFMA)
    if (t < NT - 3) { STAGE(bufS, koff); koff += 32; }

    __builtin_amdgcn_s_setprio(1);
#pragma unroll
    for (int i = 0; i < 8; ++i)
#pragma unroll
      for (int j = 0; j < 4; ++j)
        acc[i][j] = __builtin_amdgcn_mfma_f32_16x16x32_bf16(af[i], bf[j],
                                                            acc[i][j], 0, 0, 0);
    __builtin_amdgcn_s_setprio(0);

    // counted vmcnt: require tile t+1 resident; keep t+2/t+3 in flight
    if (t < NT - 3)       asm volatile("s_waitcnt vmcnt(8)" ::: "memory");
    else if (t == NT - 3) asm volatile("s_waitcnt vmcnt(4)" ::: "memory");
    else if (t == NT - 2) asm volatile("s_waitcnt vmcnt(0)" ::: "memory");
    __builtin_amdgcn_sched_barrier(0);
    if (t < NT - 1) {
      __builtin_amdgcn_s_barrier();
      __builtin_amdgcn_sched_barrier(0);
    }
    cur = (cur == 2) ? 0 : cur + 1;
  }
#undef STAGE

  // ---- epilogue: C/D layout col=lane&15, row=(lane>>4)*4+reg ---------------
#pragma unroll
  for (int j = 0; j < 4; ++j) {
    const int col = colBase + wn + j * 16 + fr;
    const float bv = bias[col];
#pragma unroll
    for (int i = 0; i < 8; ++i) {
      const int r0 = rowBase + wm + i * 16 + q * 4;
#pragma unroll
      for (int r = 0; r < 4; ++r)
        out[(size_t)(r0 + r) * N_DIM + col] = acc[i][j][r] + bv;
    }
  }
}

extern "C" void kernel_launch(void* const* d_in, const int* in_sizes, int n_in,
                              void* d_out, int out_size, void* d_ws, size_t ws_size,
                              hipStream_t stream) {
  const float* x    = (const float*)d_in[0];  // (4,2048,4096)
  const float* A    = (const float*)d_in[1];  // (64,4096)
  const float* B    = (const float*)d_in[2];  // (4096,64)
  const float* W    = (const float*)d_in[3];  // (4096,4096)
  const float* bias = (const float*)d_in[4];  // (4096,)
  float* out = (float*)d_out;

  // workspace layout (all 16B-aligned):
  //   xext  [8192][4160] bf16  = 68.16 MB
  //   wext  [4096][4160] bf16  = 34.08 MB
  //   abf   [64][4096]   bf16  =  0.52 MB
  //   zpart [8][8192][64] fp32 = 16.78 MB
  unsigned short* xext = (unsigned short*)d_ws;
  unsigned short* wext = xext + (size_t)M_DIM * KX;
  unsigned short* abf  = wext + (size_t)N_DIM * KX;
  float*          zpart = (float*)(abf + (size_t)R_DIM * DK);

  // x -> x_ext[:, :4096]
  cvt_bf16_kernel<<<(M_DIM * DK / 8 + 255) / 256, 256, 0, stream>>>(
      x, xext, 12, 4095, KX, 0, (long long)M_DIM * DK);
  // W -> w_ext[:, :4096]
  cvt_bf16_kernel<<<(N_DIM * DK / 8 + 255) / 256, 256, 0, stream>>>(
      W, wext, 12, 4095, KX, 0, (long long)N_DIM * DK);
  // B -> w_ext[:, 4096:]
  cvt_bf16_kernel<<<(N_DIM * R_DIM / 8 + 255) / 256, 256, 0, stream>>>(
      B, wext, 6, 63, KX, 4096, (long long)N_DIM * R_DIM);
  // A -> abf
  cvt_bf16_kernel<<<(R_DIM * DK / 8 + 255) / 256, 256, 0, stream>>>(
      A, abf, 12, 4095, DK, 0, (long long)R_DIM * DK);

  // z partials via MFMA split-K GEMM
  dim3 zgrid(M_DIM / 128, SPLITK);  // 64 x 8
  zgemm_kernel<<<zgrid, 256, 0, stream>>>(xext, abf, zpart);
  // reduce + soft-topk mask -> x_ext[:, 4096:]
  mask_kernel<<<M_DIM / 4, 256, 0, stream>>>(zpart, xext);

  // main GEMM: 512 blocks (32 bm x 16 bn), 512 threads, 96 KB dynamic LDS
  gemm_kernel<<<dim3(32 * 16), 512, 3 * BUFS * sizeof(unsigned short), stream>>>(
      xext, wext, bias, out);
}

// Round 2
// 544.700 us; speedup vs baseline: 1.1300x; 1.0217x over previous
//
#include <hip/hip_runtime.h>
#include <hip/hip_bf16.h>

// Problem constants (fixed shapes from setup_inputs)
#define M_DIM 8192   // B*S = 4*2048
#define N_DIM 4096   // D_OUT
#define DK    4096   // D_IN
#define R_DIM 64
#define KX    4160   // DK + R_DIM (K-extended GEMM)
#define SPLITK 8
#define KCHUNK (DK / SPLITK)  // 512
// SCALE = ALPHA/K = 16/16 = 1.0

// main gemm tiling: 256x256 tile, BK=32, 4-deep LDS ring, 8 waves (2Mx4N)
#define BM 256
#define BN 256
#define BK 32
#define NT (KX / BK)            // 130 K-tiles
#define ATILE (BM * BK)         // 8192 shorts = 16 KB per operand per buffer
#define BUFS (2 * ATILE)        // 16384 shorts per ring slot (A + B)
#define RING 4                  // 4 * 32 KB = 128 KB LDS

typedef __bf16 bf16x8 __attribute__((ext_vector_type(8)));
typedef float f32x4 __attribute__((ext_vector_type(4)));
typedef unsigned short ushort8 __attribute__((ext_vector_type(8)));

__device__ __forceinline__ unsigned short f2bf_rne(float f) {
  union { float f; unsigned int u; } v; v.f = f;
  unsigned int u = v.u;
  return (unsigned short)((u + 0x7fffu + ((u >> 16) & 1u)) >> 16);
}

// async global->LDS, 16B per lane; lds dest is wave-uniform base + lane*16
__device__ __forceinline__ void load16_to_lds(const void* g, void* l) {
  __builtin_amdgcn_global_load_lds(
      (__attribute__((address_space(1))) void*)(unsigned long long)(const char*)g,
      (__attribute__((address_space(3))) void*)(unsigned int)(unsigned long long)(char*)l,
      16, 0, 0);
}

// ---------------- fp32 -> bf16 conversion into strided layout ----------------
__global__ __launch_bounds__(256) void cvt_bf16_kernel(
    const float* __restrict__ src, unsigned short* __restrict__ dst,
    int shift, int mask, int rowstride, int coloff, long long total) {
  long long idx = ((long long)blockIdx.x * 256 + threadIdx.x) * 8;
  if (idx >= total) return;
  long long row = idx >> shift;
  int col = (int)(idx & mask);
  float4 f0 = *(const float4*)(src + idx);
  float4 f1 = *(const float4*)(src + idx + 4);
  ushort8 o;
  o[0] = f2bf_rne(f0.x); o[1] = f2bf_rne(f0.y);
  o[2] = f2bf_rne(f0.z); o[3] = f2bf_rne(f0.w);
  o[4] = f2bf_rne(f1.x); o[5] = f2bf_rne(f1.y);
  o[6] = f2bf_rne(f1.z); o[7] = f2bf_rne(f1.w);
  *(ushort8*)(dst + row * (long long)rowstride + coloff + col) = o;
}

// ---------------- z partials: zpart[kc] = xext[:, kc*512:(kc+1)*512] @ Abf^T ----------------
__global__ __launch_bounds__(256) void zgemm_kernel(
    const unsigned short* __restrict__ Xg,   // [M_DIM][KX] bf16
    const unsigned short* __restrict__ Ab,   // [R_DIM][DK] bf16
    float* __restrict__ zpart) {             // [SPLITK][M_DIM][64] fp32
  __shared__ unsigned short As[128][32];  // 8 KB (x rows)
  __shared__ unsigned short Bs[64][32];   // 4 KB (A rows)

  const int tid = threadIdx.x;
  const int wave = tid >> 6;
  const int lane = tid & 63;
  const int rowBase = blockIdx.x * 128;
  const int kc = blockIdx.y;
  const int kBase = kc * KCHUNK;
  const int wm = wave * 32;

  const int c0 = wave, c1 = wave + 4;
  const int srow = lane >> 2;
  const int sseg = (lane & 3) * 8;

  const unsigned short* aP0 = Xg + (size_t)(rowBase + c0 * 16 + srow) * KX + kBase + sseg;
  const unsigned short* aP1 = Xg + (size_t)(rowBase + c1 * 16 + srow) * KX + kBase + sseg;
  const unsigned short* bP0 = Ab + (size_t)(wave * 16 + srow) * DK + kBase + sseg;
  unsigned short* aL0 = &As[c0 * 16][0];
  unsigned short* aL1 = &As[c1 * 16][0];
  unsigned short* bL0 = &Bs[wave * 16][0];

  f32x4 acc[2][4] = {};
  const int fr = lane & 15;
  const int fk = (lane >> 4) * 8;

  for (int k0 = 0; k0 < KCHUNK; k0 += 32) {
    __syncthreads();
    load16_to_lds(aP0 + k0, aL0);
    load16_to_lds(aP1 + k0, aL1);
    load16_to_lds(bP0 + k0, bL0);
    __syncthreads();

    bf16x8 afrag[2], bfrag[4];
#pragma unroll
    for (int i = 0; i < 2; ++i)
      afrag[i] = *(const bf16x8*)&As[wm + i * 16 + fr][fk];
#pragma unroll
    for (int j = 0; j < 4; ++j)
      bfrag[j] = *(const bf16x8*)&Bs[j * 16 + fr][fk];
#pragma unroll
    for (int i = 0; i < 2; ++i)
#pragma unroll
      for (int j = 0; j < 4; ++j)
        acc[i][j] = __builtin_amdgcn_mfma_f32_16x16x32_bf16(afrag[i], bfrag[j],
                                                            acc[i][j], 0, 0, 0);
  }

  const int quad = lane >> 4;
#pragma unroll
  for (int j = 0; j < 4; ++j) {
    int col = j * 16 + fr;
#pragma unroll
    for (int i = 0; i < 2; ++i) {
      int row0 = rowBase + wm + i * 16 + quad * 4;
#pragma unroll
      for (int r = 0; r < 4; ++r)
        zpart[((size_t)kc * M_DIM + row0 + r) * R_DIM + col] = acc[i][j][r];
    }
  }
}

// ---------------- reduce partials, soft top-k mask, write bf16 into x_ext tail ----------------
__global__ __launch_bounds__(256) void mask_kernel(
    const float* __restrict__ zpart, unsigned short* __restrict__ xext) {
  const int wave = threadIdx.x >> 6;
  const int lane = threadIdx.x & 63;
  const int row = blockIdx.x * 4 + wave;

  float v = 0.f;
#pragma unroll
  for (int k = 0; k < SPLITK; ++k)
    v += zpart[((size_t)k * M_DIM + row) * R_DIM + lane];

  float a = fabsf(v);
  // rank-select the 16th-largest |z| (tie-safe): cnt_gt <= 15 < cnt_ge
  int cnt_gt = 0, cnt_ge = 0;
#pragma unroll
  for (int i = 0; i < 64; ++i) {
    float o = __shfl(a, i);
    cnt_gt += (o > a) ? 1 : 0;
    cnt_ge += (o >= a) ? 1 : 0;
  }
  float cand = (cnt_gt <= 15 && cnt_ge > 15) ? a : -1.f;
#pragma unroll
  for (int off = 32; off; off >>= 1) cand = fmaxf(cand, __shfl_xor(cand, off));
  float thr = cand;
  float mask = 1.f / (1.f + __expf(-(a - thr) * 10.0f));  // TEMP=0.1
  xext[(size_t)row * KX + DK + lane] = f2bf_rne(v * mask);  // SCALE == 1.0
}

// ---------------- main GEMM: out[m][n] = sum_k xext[m][k]*wext[n][k] + bias[n] ----------------
// 256x256 tile, BK=32, 8 waves (2Mx4N), 4-deep LDS ring.
// One barrier per tile; ds_read and MFMA of the SAME tile adjacent so the
// compiler's counted lgkmcnt streams MFMAs while later frags are in flight
// (this is the lever vs round 1's read->drain->barrier->MFMA serialization).
// Counted vmcnt (never 0 in main loop) keeps 2-3 stages flying across barriers.
__global__ __launch_bounds__(512, 2) void gemm_kernel(
    const unsigned short* __restrict__ Ag,   // [M_DIM][KX] bf16
    const unsigned short* __restrict__ Bg,   // [N_DIM][KX] bf16
    const float* __restrict__ bias,
    float* __restrict__ out) {
  extern __shared__ unsigned short sm[];  // RING * BUFS shorts = 128 KB

  const int tid = threadIdx.x;
  const int w = tid >> 6;
  const int lane = tid & 63;

  // T1: 512 blocks = 8 XCDs x 64; each XCD gets 4 consecutive bm rows
  const int bid = blockIdx.x;
  const int swz = (bid & 7) * 64 + (bid >> 3);
  const int bm = swz >> 4;   // 0..31
  const int bn = swz & 15;   // 0..15
  const int rowBase = bm * BM;
  const int colBase = bn * BN;

  // wave tile: 2 (M) x 4 (N); per-wave output 128x64
  const int wm = (w >> 2) * 128;
  const int wn = (w & 3) * 64;

  // ---- staging setup -------------------------------------------------------
  // LDS dest is linear (wave-uniform base + lane*16B) -> lane L writes
  // row (chunk*16 + L>>2), 16B-slot (L&3). To realize the read-side swizzle
  // slot' = slot ^ ((row>>1)&3), pre-swizzle the GLOBAL source segment.
  const int srow = lane >> 2;                                // 0..15
  const int sseg = (((lane & 3) ^ ((lane >> 3) & 3)) * 8);   // swizzled 8-short seg
  const int c0 = w * 2, c1 = w * 2 + 1;                      // 16-row chunks
  const unsigned short* aS0 = Ag + (size_t)(rowBase + c0 * 16 + srow) * KX + sseg;
  const unsigned short* aS1 = Ag + (size_t)(rowBase + c1 * 16 + srow) * KX + sseg;
  const unsigned short* bS0 = Bg + (size_t)(colBase + c0 * 16 + srow) * KX + sseg;
  const unsigned short* bS1 = Bg + (size_t)(colBase + c1 * 16 + srow) * KX + sseg;
  const int aD0 = c0 * 512, aD1 = c1 * 512;                  // shorts, wave-uniform
  const int bD0 = ATILE + c0 * 512, bD1 = ATILE + c1 * 512;

#define STAGE(bufS, koff)                                \
  do {                                                   \
    load16_to_lds(aS0 + (koff), &sm[(bufS) + aD0]);      \
    load16_to_lds(aS1 + (koff), &sm[(bufS) + aD1]);      \
    load16_to_lds(bS0 + (koff), &sm[(bufS) + bD0]);      \
    load16_to_lds(bS1 + (koff), &sm[(bufS) + bD1]);      \
  } while (0)

  // ---- prologue: fill the 4-deep ring (tiles 0..3), 16 loads in flight ----
  STAGE(0 * BUFS, 0);
  STAGE(1 * BUFS, 32);
  STAGE(2 * BUFS, 64);
  STAGE(3 * BUFS, 96);
  asm volatile("s_waitcnt vmcnt(12)" ::: "memory");  // tile 0 landed; 1..3 in flight
  __builtin_amdgcn_sched_barrier(0);
  __builtin_amdgcn_s_barrier();
  __builtin_amdgcn_sched_barrier(0);

  // ---- main loop -----------------------------------------------------------
  f32x4 acc[8][4] = {};
  const int fr = lane & 15;
  const int q = lane >> 4;
  const int rdc = ((q ^ ((fr >> 1) & 3)) * 8);  // T2 read-side XOR (2-way = free)

  int bufS = 0;     // ring slot base (shorts) holding tile t
  int koff = 128;   // k-offset (shorts) of next tile to stage (tile 4)
  for (int t = 0; t < NT; ++t) {
    __builtin_amdgcn_s_setprio(1);
    // ds_read all fragments for this tile (12 x ds_read_b128 per lane),
    // immediately followed by the MFMAs that consume them -- NO fence between,
    // so the scheduler interleaves them with counted lgkmcnt.
    bf16x8 af[8], bf[4];
#pragma unroll
    for (int i = 0; i < 8; ++i)
      af[i] = *(const bf16x8*)&sm[bufS + (wm + i * 16 + fr) * 32 + rdc];
#pragma unroll
    for (int j = 0; j < 4; ++j)
      bf[j] = *(const bf16x8*)&sm[bufS + ATILE + (wn + j * 16 + fr) * 32 + rdc];

#pragma unroll
    for (int i = 0; i < 8; ++i)
#pragma unroll
      for (int j = 0; j < 4; ++j)
        acc[i][j] = __builtin_amdgcn_mfma_f32_16x16x32_bf16(af[i], bf[j],
                                                            acc[i][j], 0, 0, 0);
    __builtin_amdgcn_s_setprio(0);

    // single wait point: all my LDS reads done (free the slot) + stage(t+1)
    // resident (counted vmcnt -- keep 2 newest stages in flight)
    if (t < NT - 3)
      asm volatile("s_waitcnt vmcnt(8) lgkmcnt(0)" ::: "memory");
    else if (t == NT - 3)
      asm volatile("s_waitcnt vmcnt(4) lgkmcnt(0)" ::: "memory");
    else if (t == NT - 2)
      asm volatile("s_waitcnt vmcnt(0) lgkmcnt(0)" ::: "memory");
    else
      asm volatile("s_waitcnt lgkmcnt(0)" ::: "memory");
    __builtin_amdgcn_sched_barrier(0);
    if (t < NT - 1) {
      __builtin_amdgcn_s_barrier();
      __builtin_amdgcn_sched_barrier(0);
      // refill the just-freed slot with tile t+4 (flies during next 3 tiles)
      if (t < NT - 4) { STAGE(bufS, koff); koff += 32; }
    }
    bufS = (bufS + BUFS) & (RING * BUFS - 1);
  }
#undef STAGE

  // ---- epilogue: C/D layout col=lane&15, row=(lane>>4)*4+reg ---------------
#pragma unroll
  for (int j = 0; j < 4; ++j) {
    const int col = colBase + wn + j * 16 + fr;
    const float bv = bias[col];
#pragma unroll
    for (int i = 0; i < 8; ++i) {
      const int r0 = rowBase + wm + i * 16 + q * 4;
#pragma unroll
      for (int r = 0; r < 4; ++r)
        out[(size_t)(r0 + r) * N_DIM + col] = acc[i][j][r] + bv;
    }
  }
}

extern "C" void kernel_launch(void* const* d_in, const int* in_sizes, int n_in,
                              void* d_out, int out_size, void* d_ws, size_t ws_size,
                              hipStream_t stream) {
  const float* x    = (const float*)d_in[0];  // (4,2048,4096)
  const float* A    = (const float*)d_in[1];  // (64,4096)
  const float* B    = (const float*)d_in[2];  // (4096,64)
  const float* W    = (const float*)d_in[3];  // (4096,4096)
  const float* bias = (const float*)d_in[4];  // (4096,)
  float* out = (float*)d_out;

  // workspace layout (all 16B-aligned):
  //   xext  [8192][4160] bf16  = 68.16 MB
  //   wext  [4096][4160] bf16  = 34.08 MB
  //   abf   [64][4096]   bf16  =  0.52 MB
  //   zpart [8][8192][64] fp32 = 16.78 MB
  unsigned short* xext = (unsigned short*)d_ws;
  unsigned short* wext = xext + (size_t)M_DIM * KX;
  unsigned short* abf  = wext + (size_t)N_DIM * KX;
  float*          zpart = (float*)(abf + (size_t)R_DIM * DK);

  // x -> x_ext[:, :4096]
  cvt_bf16_kernel<<<(M_DIM * DK / 8 + 255) / 256, 256, 0, stream>>>(
      x, xext, 12, 4095, KX, 0, (long long)M_DIM * DK);
  // W -> w_ext[:, :4096]
  cvt_bf16_kernel<<<(N_DIM * DK / 8 + 255) / 256, 256, 0, stream>>>(
      W, wext, 12, 4095, KX, 0, (long long)N_DIM * DK);
  // B -> w_ext[:, 4096:]
  cvt_bf16_kernel<<<(N_DIM * R_DIM / 8 + 255) / 256, 256, 0, stream>>>(
      B, wext, 6, 63, KX, 4096, (long long)N_DIM * R_DIM);
  // A -> abf
  cvt_bf16_kernel<<<(R_DIM * DK / 8 + 255) / 256, 256, 0, stream>>>(
      A, abf, 12, 4095, DK, 0, (long long)R_DIM * DK);

  // z partials via MFMA split-K GEMM
  dim3 zgrid(M_DIM / 128, SPLITK);  // 64 x 8
  zgemm_kernel<<<zgrid, 256, 0, stream>>>(xext, abf, zpart);
  // reduce + soft-topk mask -> x_ext[:, 4096:]
  mask_kernel<<<M_DIM / 4, 256, 0, stream>>>(zpart, xext);

  // main GEMM: 512 blocks (32 bm x 16 bn), 512 threads, 128 KB dynamic LDS
  gemm_kernel<<<dim3(32 * 16), 512, RING * BUFS * sizeof(unsigned short), stream>>>(
      xext, wext, bias, out);
}

// Round 3
// 531.821 us; speedup vs baseline: 1.1574x; 1.0242x over previous
//
#include <hip/hip_runtime.h>
#include <hip/hip_bf16.h>

// Problem constants (fixed shapes from setup_inputs)
#define M_DIM 8192   // B*S = 4*2048
#define N_DIM 4096   // D_OUT
#define DK    4096   // D_IN
#define R_DIM 64
#define KX    4160   // DK + R_DIM (K-extended GEMM)
#define SPLITK 8
#define KCHUNK (DK / SPLITK)  // 512
// SCALE = ALPHA/K = 16/16 = 1.0

// main gemm tiling: 256x256 tile, BK=32, 4-deep LDS ring, 8 waves (2Mx4N)
#define BM 256
#define BN 256
#define BK 32
#define NT (KX / BK)            // 130 K-tiles
#define ATILE (BM * BK)         // 8192 shorts = 16 KB per operand per buffer
#define BUFS (2 * ATILE)        // 16384 shorts per ring slot (A + B)
#define RING 4                  // 4 * 32 KB = 128 KB LDS

typedef __bf16 bf16x8 __attribute__((ext_vector_type(8)));
typedef float f32x4 __attribute__((ext_vector_type(4)));
typedef unsigned short ushort8 __attribute__((ext_vector_type(8)));

__device__ __forceinline__ unsigned short f2bf_rne(float f) {
  union { float f; unsigned int u; } v; v.f = f;
  unsigned int u = v.u;
  return (unsigned short)((u + 0x7fffu + ((u >> 16) & 1u)) >> 16);
}

// async global->LDS, 16B per lane; lds dest is wave-uniform base + lane*16
__device__ __forceinline__ void load16_to_lds(const void* g, void* l) {
  __builtin_amdgcn_global_load_lds(
      (__attribute__((address_space(1))) void*)(unsigned long long)(const char*)g,
      (__attribute__((address_space(3))) void*)(unsigned int)(unsigned long long)(char*)l,
      16, 0, 0);
}

// ---------------- fp32 -> bf16 conversion, all four tensors in ONE launch ----------------
// job ranges are exact multiples of 2048 elems (= 1 block) -> block-uniform branch
__global__ __launch_bounds__(256) void cvt_all_kernel(
    const float* __restrict__ x, const float* __restrict__ W,
    const float* __restrict__ B, const float* __restrict__ A,
    unsigned short* __restrict__ xext, unsigned short* __restrict__ wext,
    unsigned short* __restrict__ abf) {
  const int b = blockIdx.x;
  const float* src; unsigned short* dst;
  int shift, mask, rowstride, coloff; long long base;
  if (b < 16384)      { src = x; dst = xext; shift = 12; mask = 4095; rowstride = KX; coloff = 0;  base = (long long)b * 2048; }
  else if (b < 24576) { src = W; dst = wext; shift = 12; mask = 4095; rowstride = KX; coloff = 0;  base = (long long)(b - 16384) * 2048; }
  else if (b < 24704) { src = B; dst = wext; shift = 6;  mask = 63;   rowstride = KX; coloff = DK; base = (long long)(b - 24576) * 2048; }
  else                { src = A; dst = abf;  shift = 12; mask = 4095; rowstride = DK; coloff = 0;  base = (long long)(b - 24704) * 2048; }
  long long idx = base + (long long)threadIdx.x * 8;
  long long row = idx >> shift;
  int col = (int)(idx & mask);
  float4 f0 = *(const float4*)(src + idx);
  float4 f1 = *(const float4*)(src + idx + 4);
  ushort8 o;
  o[0] = f2bf_rne(f0.x); o[1] = f2bf_rne(f0.y);
  o[2] = f2bf_rne(f0.z); o[3] = f2bf_rne(f0.w);
  o[4] = f2bf_rne(f1.x); o[5] = f2bf_rne(f1.y);
  o[6] = f2bf_rne(f1.z); o[7] = f2bf_rne(f1.w);
  *(ushort8*)(dst + row * (long long)rowstride + coloff + col) = o;
}

// ---------------- z partials: zpart[kc] = xext[:, kc*512:(kc+1)*512] @ Abf^T ----------------
__global__ __launch_bounds__(256) void zgemm_kernel(
    const unsigned short* __restrict__ Xg,   // [M_DIM][KX] bf16
    const unsigned short* __restrict__ Ab,   // [R_DIM][DK] bf16
    float* __restrict__ zpart) {             // [SPLITK][M_DIM][64] fp32
  __shared__ unsigned short As[128][32];  // 8 KB (x rows)
  __shared__ unsigned short Bs[64][32];   // 4 KB (A rows)

  const int tid = threadIdx.x;
  const int wave = tid >> 6;
  const int lane = tid & 63;
  const int rowBase = blockIdx.x * 128;
  const int kc = blockIdx.y;
  const int kBase = kc * KCHUNK;
  const int wm = wave * 32;

  const int c0 = wave, c1 = wave + 4;
  const int srow = lane >> 2;
  const int sseg = (lane & 3) * 8;

  const unsigned short* aP0 = Xg + (size_t)(rowBase + c0 * 16 + srow) * KX + kBase + sseg;
  const unsigned short* aP1 = Xg + (size_t)(rowBase + c1 * 16 + srow) * KX + kBase + sseg;
  const unsigned short* bP0 = Ab + (size_t)(wave * 16 + srow) * DK + kBase + sseg;
  unsigned short* aL0 = &As[c0 * 16][0];
  unsigned short* aL1 = &As[c1 * 16][0];
  unsigned short* bL0 = &Bs[wave * 16][0];

  f32x4 acc[2][4] = {};
  const int fr = lane & 15;
  const int fk = (lane >> 4) * 8;

  for (int k0 = 0; k0 < KCHUNK; k0 += 32) {
    __syncthreads();
    load16_to_lds(aP0 + k0, aL0);
    load16_to_lds(aP1 + k0, aL1);
    load16_to_lds(bP0 + k0, bL0);
    __syncthreads();

    bf16x8 afrag[2], bfrag[4];
#pragma unroll
    for (int i = 0; i < 2; ++i)
      afrag[i] = *(const bf16x8*)&As[wm + i * 16 + fr][fk];
#pragma unroll
    for (int j = 0; j < 4; ++j)
      bfrag[j] = *(const bf16x8*)&Bs[j * 16 + fr][fk];
#pragma unroll
    for (int i = 0; i < 2; ++i)
#pragma unroll
      for (int j = 0; j < 4; ++j)
        acc[i][j] = __builtin_amdgcn_mfma_f32_16x16x32_bf16(afrag[i], bfrag[j],
                                                            acc[i][j], 0, 0, 0);
  }

  const int quad = lane >> 4;
#pragma unroll
  for (int j = 0; j < 4; ++j) {
    int col = j * 16 + fr;
#pragma unroll
    for (int i = 0; i < 2; ++i) {
      int row0 = rowBase + wm + i * 16 + quad * 4;
#pragma unroll
      for (int r = 0; r < 4; ++r)
        zpart[((size_t)kc * M_DIM + row0 + r) * R_DIM + col] = acc[i][j][r];
    }
  }
}

// ---------------- reduce partials, soft top-k mask, write bf16 into x_ext tail ----------------
__global__ __launch_bounds__(256) void mask_kernel(
    const float* __restrict__ zpart, unsigned short* __restrict__ xext) {
  const int wave = threadIdx.x >> 6;
  const int lane = threadIdx.x & 63;
  const int row = blockIdx.x * 4 + wave;

  float v = 0.f;
#pragma unroll
  for (int k = 0; k < SPLITK; ++k)
    v += zpart[((size_t)k * M_DIM + row) * R_DIM + lane];

  float a = fabsf(v);
  // rank-select the 16th-largest |z| (tie-safe): cnt_gt <= 15 < cnt_ge
  int cnt_gt = 0, cnt_ge = 0;
#pragma unroll
  for (int i = 0; i < 64; ++i) {
    float o = __shfl(a, i);
    cnt_gt += (o > a) ? 1 : 0;
    cnt_ge += (o >= a) ? 1 : 0;
  }
  float cand = (cnt_gt <= 15 && cnt_ge > 15) ? a : -1.f;
#pragma unroll
  for (int off = 32; off; off >>= 1) cand = fmaxf(cand, __shfl_xor(cand, off));
  float thr = cand;
  float mask = 1.f / (1.f + __expf(-(a - thr) * 10.0f));  // TEMP=0.1
  xext[(size_t)row * KX + DK + lane] = f2bf_rne(v * mask);  // SCALE == 1.0
}

// ---------------- main GEMM: out[m][n] = sum_k xext[m][k]*wext[n][k] + bias[n] ----------------
// 256x256 tile, BK=32, 8 waves (2Mx4N), 4-deep LDS ring, REGISTER-double-buffered
// fragments: tile t+1's ds_reads issue BEFORE tile t's MFMAs (slot t+1 residency
// guaranteed block-wide by the previous barrier), so LDS latency + port time hide
// under MFMA issue. Post-MFMA wait is counted: vmcnt(4) (own stage t+2 done,
// stage t+3 stays in flight) + lgkmcnt(12) (DS in-order => all slot-t reads done,
// the 12 fragsNEXT reads stay outstanding). Barrier then makes slot(t+2) resident
// block-wide and slot(t) safe to overwrite.
__global__ __launch_bounds__(512, 2) void gemm_kernel(
    const unsigned short* __restrict__ Ag,   // [M_DIM][KX] bf16
    const unsigned short* __restrict__ Bg,   // [N_DIM][KX] bf16
    const float* __restrict__ bias,
    float* __restrict__ out) {
  extern __shared__ unsigned short sm[];  // RING * BUFS shorts = 128 KB

  const int tid = threadIdx.x;
  const int w = tid >> 6;
  const int lane = tid & 63;

  // T1: 512 blocks = 8 XCDs x 64; each XCD gets 4 consecutive bm rows
  const int bid = blockIdx.x;
  const int swz = (bid & 7) * 64 + (bid >> 3);
  const int bm = swz >> 4;   // 0..31
  const int bn = swz & 15;   // 0..15
  const int rowBase = bm * BM;
  const int colBase = bn * BN;

  // wave tile: 2 (M) x 4 (N); per-wave output 128x64
  const int wm = (w >> 2) * 128;
  const int wn = (w & 3) * 64;

  // ---- staging setup -------------------------------------------------------
  // LDS dest is linear (wave-uniform base + lane*16B) -> lane L writes
  // row (chunk*16 + L>>2), 16B-slot (L&3). To realize the read-side swizzle
  // slot' = slot ^ ((row>>1)&3), pre-swizzle the GLOBAL source segment.
  const int srow = lane >> 2;                                // 0..15
  const int sseg = (((lane & 3) ^ ((lane >> 3) & 3)) * 8);   // swizzled 8-short seg
  const int c0 = w * 2, c1 = w * 2 + 1;                      // 16-row chunks
  const unsigned short* aS0 = Ag + (size_t)(rowBase + c0 * 16 + srow) * KX + sseg;
  const unsigned short* aS1 = Ag + (size_t)(rowBase + c1 * 16 + srow) * KX + sseg;
  const unsigned short* bS0 = Bg + (size_t)(colBase + c0 * 16 + srow) * KX + sseg;
  const unsigned short* bS1 = Bg + (size_t)(colBase + c1 * 16 + srow) * KX + sseg;
  const int aD0 = c0 * 512, aD1 = c1 * 512;                  // shorts, wave-uniform
  const int bD0 = ATILE + c0 * 512, bD1 = ATILE + c1 * 512;

#define STAGE(bufS, koff)                                \
  do {                                                   \
    load16_to_lds(aS0 + (koff), &sm[(bufS) + aD0]);      \
    load16_to_lds(aS1 + (koff), &sm[(bufS) + aD1]);      \
    load16_to_lds(bS0 + (koff), &sm[(bufS) + bD0]);      \
    load16_to_lds(bS1 + (koff), &sm[(bufS) + bD1]);      \
  } while (0)

  f32x4 acc[8][4] = {};
  const int fr = lane & 15;
  const int q = lane >> 4;
  const int rdc = ((q ^ ((fr >> 1) & 3)) * 8);  // T2 read-side XOR (2-way = free)

#define RD_FRAGS(AF, BF, S)                                                   \
  do {                                                                        \
    _Pragma("unroll")                                                         \
    for (int i_ = 0; i_ < 8; ++i_)                                            \
      AF[i_] = *(const bf16x8*)&sm[(S) + (wm + i_ * 16 + fr) * 32 + rdc];     \
    _Pragma("unroll")                                                         \
    for (int j_ = 0; j_ < 4; ++j_)                                            \
      BF[j_] = *(const bf16x8*)&sm[(S) + ATILE + (wn + j_ * 16 + fr) * 32 + rdc]; \
  } while (0)

#define MFMA_ALL(AF, BF)                                                      \
  do {                                                                        \
    __builtin_amdgcn_s_setprio(1);                                            \
    _Pragma("unroll")                                                         \
    for (int i_ = 0; i_ < 8; ++i_)                                            \
      _Pragma("unroll")                                                       \
      for (int j_ = 0; j_ < 4; ++j_)                                          \
        acc[i_][j_] = __builtin_amdgcn_mfma_f32_16x16x32_bf16(                \
            AF[i_], BF[j_], acc[i_][j_], 0, 0, 0);                            \
    __builtin_amdgcn_s_setprio(0);                                            \
  } while (0)

#define WAIT_BARRIER(VM)                                                      \
  do {                                                                        \
    asm volatile("s_waitcnt vmcnt(" #VM ") lgkmcnt(12)" ::: "memory");        \
    __builtin_amdgcn_sched_barrier(0);                                        \
    __builtin_amdgcn_s_barrier();                                             \
    __builtin_amdgcn_sched_barrier(0);                                        \
  } while (0)

  // ---- prologue: fill the 4-deep ring (tiles 0..3), 16 loads in flight ----
  STAGE(0 * BUFS, 0);
  STAGE(1 * BUFS, 32);
  STAGE(2 * BUFS, 64);
  STAGE(3 * BUFS, 96);
  // slots 0 AND 1 must be resident block-wide before iter 0 (it reads slot 1)
  asm volatile("s_waitcnt vmcnt(8)" ::: "memory");
  __builtin_amdgcn_sched_barrier(0);
  __builtin_amdgcn_s_barrier();
  __builtin_amdgcn_sched_barrier(0);

  bf16x8 afA[8], bfA[4], afB[8], bfB[4];
  RD_FRAGS(afA, bfA, 0);  // fragments of tile 0

  // ---- main loop: pairs t=(tp, tp+1), tp = 0..124; stages tiles 4..129 -----
  int koff = 128;
  for (int tp = 0; tp < 126; tp += 2) {
    const int s0 = (tp & 3) * BUFS;
    const int s1 = ((tp + 1) & 3) * BUFS;
    const int s2 = ((tp + 2) & 3) * BUFS;
    // t = tp: prefetch fragsB <- slot(t+1), compute tile t on fragsA
    RD_FRAGS(afB, bfB, s1);
    MFMA_ALL(afA, bfA);
    WAIT_BARRIER(4);
    STAGE(s0, koff); koff += 32;   // tile tp+4 into just-freed slot
    // t = tp+1: prefetch fragsA <- slot(t+1), compute on fragsB
    RD_FRAGS(afA, bfA, s2);
    MFMA_ALL(afB, bfB);
    WAIT_BARRIER(4);
    STAGE(s1, koff); koff += 32;   // tile tp+5
  }

  // ---- tail: tiles 126..129 (no more staging after tile 129) ---------------
  // t=126: fragsA holds tile 126
  RD_FRAGS(afB, bfB, (127 & 3) * BUFS);
  MFMA_ALL(afA, bfA);
  WAIT_BARRIER(4);                 // slot(128) resident block-wide
  // t=127
  RD_FRAGS(afA, bfA, (128 & 3) * BUFS);
  MFMA_ALL(afB, bfB);
  WAIT_BARRIER(0);                 // slot(129) resident block-wide
  // t=128
  RD_FRAGS(afB, bfB, (129 & 3) * BUFS);
  MFMA_ALL(afA, bfA);
  // t=129 (compiler inserts lgkmcnt for the final frag reads)
  MFMA_ALL(afB, bfB);

#undef STAGE
#undef RD_FRAGS
#undef MFMA_ALL
#undef WAIT_BARRIER

  // ---- epilogue: C/D layout col=lane&15, row=(lane>>4)*4+reg ---------------
#pragma unroll
  for (int j = 0; j < 4; ++j) {
    const int col = colBase + wn + j * 16 + fr;
    const float bv = bias[col];
#pragma unroll
    for (int i = 0; i < 8; ++i) {
      const int r0 = rowBase + wm + i * 16 + q * 4;
#pragma unroll
      for (int r = 0; r < 4; ++r)
        out[(size_t)(r0 + r) * N_DIM + col] = acc[i][j][r] + bv;
    }
  }
}

extern "C" void kernel_launch(void* const* d_in, const int* in_sizes, int n_in,
                              void* d_out, int out_size, void* d_ws, size_t ws_size,
                              hipStream_t stream) {
  const float* x    = (const float*)d_in[0];  // (4,2048,4096)
  const float* A    = (const float*)d_in[1];  // (64,4096)
  const float* B    = (const float*)d_in[2];  // (4096,64)
  const float* W    = (const float*)d_in[3];  // (4096,4096)
  const float* bias = (const float*)d_in[4];  // (4096,)
  float* out = (float*)d_out;

  // workspace layout (all 16B-aligned):
  //   xext  [8192][4160] bf16  = 68.16 MB
  //   wext  [4096][4160] bf16  = 34.08 MB
  //   abf   [64][4096]   bf16  =  0.52 MB
  //   zpart [8][8192][64] fp32 = 16.78 MB
  unsigned short* xext = (unsigned short*)d_ws;
  unsigned short* wext = xext + (size_t)M_DIM * KX;
  unsigned short* abf  = wext + (size_t)N_DIM * KX;
  float*          zpart = (float*)(abf + (size_t)R_DIM * DK);

  // all four fp32->bf16 conversions in one launch (saves 3 launch gaps)
  cvt_all_kernel<<<24832, 256, 0, stream>>>(x, W, B, A, xext, wext, abf);

  // z partials via MFMA split-K GEMM
  dim3 zgrid(M_DIM / 128, SPLITK);  // 64 x 8
  zgemm_kernel<<<zgrid, 256, 0, stream>>>(xext, abf, zpart);
  // reduce + soft-topk mask -> x_ext[:, 4096:]
  mask_kernel<<<M_DIM / 4, 256, 0, stream>>>(zpart, xext);

  // main GEMM: 512 blocks (32 bm x 16 bn), 512 threads, 128 KB dynamic LDS
  gemm_kernel<<<dim3(32 * 16), 512, RING * BUFS * sizeof(unsigned short), stream>>>(
      xext, wext, bias, out);
}